// Round 3
// baseline (690.792 us; speedup 1.0000x reference)
//
#include <hip/hip_runtime.h>

// y[b,o] = sum_i x[b,i]*W[i,o]*w_mask[b,i,o] + bias[o]*b_mask[b,o]
// B=32, IN_F=1024, OUT_F=4096. f32 tensors, int32 masks.
//
// Round-6 theory: R4 (occupancy 2x) and R5 (weight amortize 8x, load-return /2)
// both NEUTRAL => not latency-bound, not load-return-bound. Remaining invariants
// vs the 6.4 TB/s fill kernels: (a) strided per-block mask coverage (4 KiB of
// every 16 KiB) vs fills' contiguous ranges; (b) NT hint on mask loads.
// Fix: block owns [b, i0:i0+64, :] = 1 MiB FULLY CONTIGUOUS mask region
// (4 o-quads per thread span the whole 16 KiB row); plain (non-NT) mask loads.
// Grid 32 b x 16 chunk = 512 blocks, 2/CU; chunk in low bid bits => all 32
// b-sharers of a chunk's 1 MiB weight slice on one XCD L2.

#define B_DIM 32
#define IN_F 1024
#define OUT_F 4096
#define N_CHUNK 16
#define I_CHUNK (IN_F / N_CHUNK)    // 64 i-rows per block
#define BO (B_DIM * OUT_F)          // 131072

typedef int   v4i __attribute__((ext_vector_type(4)));
typedef float v4f __attribute__((ext_vector_type(4)));

// partial[chunk][b][o] : 16 x 32 x 4096 f32 = 8 MiB in d_ws
__global__ __launch_bounds__(256, 2) void masked_gemv_partial(
    const float* __restrict__ x,       // [B, IN_F]
    const float* __restrict__ weight,  // [IN_F, OUT_F]
    const int* __restrict__ w_mask,    // [B, IN_F, OUT_F]
    float* __restrict__ partial)
{
    const int bid   = blockIdx.x;      // b*16 + chunk
    const int b     = bid >> 4;
    const int chunk = bid & 15;
    const int i0    = chunk * I_CHUNK;

    __shared__ float xs[I_CHUNK];      // 256 B
    if (threadIdx.x < I_CHUNK)
        xs[threadIdx.x] = x[b * IN_F + i0 + threadIdx.x];
    __syncthreads();

    // thread covers o = q*1024 + tid*4, q = 0..3  -> block spans full 16 KiB row
    const int*   mptr = w_mask + ((size_t)b * IN_F + i0) * OUT_F + (threadIdx.x << 2);
    const float* wptr = weight + (size_t)i0 * OUT_F + (threadIdx.x << 2);

    v4f acc[4];
#pragma unroll
    for (int q = 0; q < 4; ++q) acc[q] = (v4f){0.f, 0.f, 0.f, 0.f};

#pragma unroll 2
    for (int i = 0; i < I_CHUNK; ++i) {
        const float  xi  = xs[i];                 // wave-uniform -> LDS broadcast
        const size_t row = (size_t)i * OUT_F;
#pragma unroll
        for (int q = 0; q < 4; ++q) {
            const v4i m = *(const v4i*)(mptr + row + q * 1024);   // plain load
            const v4f w = *(const v4f*)(wptr + row + q * 1024);
            acc[q].x = fmaf(xi * (float)m.x, w.x, acc[q].x);
            acc[q].y = fmaf(xi * (float)m.y, w.y, acc[q].y);
            acc[q].z = fmaf(xi * (float)m.z, w.z, acc[q].z);
            acc[q].w = fmaf(xi * (float)m.w, w.w, acc[q].w);
        }
    }

    float* pbase = partial + (size_t)chunk * BO + b * OUT_F + (threadIdx.x << 2);
#pragma unroll
    for (int q = 0; q < 4; ++q)
        __builtin_nontemporal_store(acc[q], (v4f*)(pbase + q * 1024));
}

__global__ __launch_bounds__(256) void reduce_bias_kernel(
    const float* __restrict__ partial,  // [N_CHUNK][B][OUT_F]
    const float* __restrict__ bias,     // [OUT_F]
    const int* __restrict__ b_mask,     // [B, OUT_F]
    float* __restrict__ out)            // [B, OUT_F]
{
    const int tid = blockIdx.x * 256 + threadIdx.x;   // [0, BO/4)
    const v4f* p4 = (const v4f*)partial;
    v4f s = {0.f, 0.f, 0.f, 0.f};
#pragma unroll
    for (int c = 0; c < N_CHUNK; ++c) {
        const v4f v = p4[(size_t)c * (BO / 4) + tid];
        s.x += v.x; s.y += v.y; s.z += v.z; s.w += v.w;
    }
    const v4i bm = ((const v4i*)b_mask)[tid];
    const v4f bi = ((const v4f*)bias)[tid & (OUT_F / 4 - 1)];
    v4f r;
    r.x = fmaf(bi.x, (float)bm.x, s.x);
    r.y = fmaf(bi.y, (float)bm.y, s.y);
    r.z = fmaf(bi.z, (float)bm.z, s.z);
    r.w = fmaf(bi.w, (float)bm.w, s.w);
    ((v4f*)out)[tid] = r;
}

extern "C" void kernel_launch(void* const* d_in, const int* in_sizes, int n_in,
                              void* d_out, int out_size, void* d_ws, size_t ws_size,
                              hipStream_t stream) {
    const float* x      = (const float*)d_in[0];
    const float* weight = (const float*)d_in[1];
    const float* bias   = (const float*)d_in[2];
    const int*   w_mask = (const int*)d_in[3];
    const int*   b_mask = (const int*)d_in[4];
    float* out     = (float*)d_out;
    float* partial = (float*)d_ws;  // 8 MiB used

    masked_gemv_partial<<<B_DIM * N_CHUNK, 256, 0, stream>>>(x, weight, w_mask, partial);
    reduce_bias_kernel<<<BO / 4 / 256, 256, 0, stream>>>(partial, bias, b_mask, out);
}